// Round 3
// baseline (565.011 us; speedup 1.0000x reference)
//
#include <hip/hip_runtime.h>

#define EPS 1e-5f
#define MV_DIM 256
#define NB 64
#define NGRADES 9

// grade(c) for c = 16*j + 4*i + s  (j = lane&15, i = float4 index, s = component)
// = popc(j) + popc(i) + popc(s);  popc over disjoint bit fields.
// Each lane owns 16 contiguous components (64B). Relative buckets indexed by
// popc(i)+popc(s) (compile-time); absolute grade base bj = popc(j) (runtime).

__device__ __forceinline__ float pick9(const float a[NGRADES], int idx) {
    float v = a[0];
#pragma unroll
    for (int k = 1; k < NGRADES; ++k) v = (idx == k) ? a[k] : v;
    return v;
}

// Load 16 comps, accumulate rel[5], expand to abs[9], butterfly within 16 lanes.
// After this, every lane of the 16-lane group holds the row's 9 grade sumsqs.
__device__ __forceinline__ void row_grade_sumsq(const float4* __restrict__ p,
                                                float4 va[4], int bj,
                                                float ab[NGRADES]) {
#pragma unroll
    for (int i = 0; i < 4; ++i) va[i] = p[i];

    float rel[5] = {0.f, 0.f, 0.f, 0.f, 0.f};
    const int PI[4] = {0, 1, 1, 2};              // popc(i)
#pragma unroll
    for (int i = 0; i < 4; ++i) {
        rel[PI[i] + 0] += va[i].x * va[i].x;
        rel[PI[i] + 1] += va[i].y * va[i].y + va[i].z * va[i].z;
        rel[PI[i] + 2] += va[i].w * va[i].w;
    }

#pragma unroll
    for (int g = 0; g < NGRADES; ++g) {
        float v = 0.f;
#pragma unroll
        for (int k = 0; k < 5; ++k) v = (g == bj + k) ? rel[k] : v;
        ab[g] = v;
    }

#pragma unroll
    for (int off = 1; off < 16; off <<= 1) {
#pragma unroll
        for (int g = 0; g < NGRADES; ++g) ab[g] += __shfl_xor(ab[g], off, 64);
    }
}

// ---------------------------------------------------------------------------
// Pass 1: batch statistics (sum nf, sum nf^2) per (nb, grade)
// 16 lanes per row; lane j<9 tracks grade j across its group's rows.
// ---------------------------------------------------------------------------
__global__ __launch_bounds__(256) void cbn_pass1(const float* __restrict__ x,
                                                 float* __restrict__ stats,
                                                 long nrows) {
    const int j  = threadIdx.x & 15;
    const int bj = __popc(j);
    const long G        = (long)blockIdx.x * 16 + (threadIdx.x >> 4);
    const long totG     = (long)gridDim.x * 16;      // multiple of 64
    const int  nb       = (int)(G & 63);             // constant across row loop

    float sA = 0.f, sB = 0.f;
    float4 va[4];
    float ab[NGRADES];

    for (long row = G; row < nrows; row += totG) {
        row_grade_sumsq((const float4*)(x + row * MV_DIM + j * 16), va, bj, ab);
        const float q2 = pick9(ab, j) + EPS;         // nf^2 for grade j (j<9)
        sA += sqrtf(q2);
        sB += q2;
    }

    if (j < NGRADES) {
        atomicAdd(&stats[nb * NGRADES + j], sA);
        atomicAdd(&stats[NB * NGRADES + nb * NGRADES + j], sB);
    }
}

// ---------------------------------------------------------------------------
// Finalize: per (nb, grade) coefficients
//   A = rsqrt(var+eps) * gamma * gs ;  B = (beta - mean*rsqrt(var+eps)*gamma) * gs
// ---------------------------------------------------------------------------
__global__ void cbn_finalize(const float* __restrict__ stats,
                             const float* __restrict__ gamma,
                             const float* __restrict__ beta,
                             const float* __restrict__ gscale,
                             float* __restrict__ coef, float invB) {
    const int t = blockIdx.x * blockDim.x + threadIdx.x;
    if (t >= NB * NGRADES) return;
    const int nb = t / NGRADES;
    const int g  = t % NGRADES;
    const float mean = stats[t] * invB;
    const float ex2  = stats[NB * NGRADES + t] * invB;
    const float var  = ex2 - mean * mean;
    const float inv  = 1.0f / sqrtf(var + EPS);
    const float ga = gamma[g * NB + nb];
    const float be = beta[g * NB + nb];
    const float gs = gscale[g];
    coef[t]                = inv * ga * gs;                // A
    coef[NB * NGRADES + t] = (be - mean * inv * ga) * gs;  // B
}

// ---------------------------------------------------------------------------
// Pass 2: recompute row grade sumsqs, apply out = x * (A + B / nf)
// ---------------------------------------------------------------------------
__global__ __launch_bounds__(256) void cbn_pass2(const float* __restrict__ x,
                                                 const float* __restrict__ coef,
                                                 float* __restrict__ out,
                                                 long nrows) {
    __shared__ float cA[NB * NGRADES];
    __shared__ float cB[NB * NGRADES];
    for (int i = threadIdx.x; i < NB * NGRADES; i += 256) {
        cA[i] = coef[i];
        cB[i] = coef[NB * NGRADES + i];
    }
    __syncthreads();

    const int j  = threadIdx.x & 15;
    const int bj = __popc(j);
    const long G    = (long)blockIdx.x * 16 + (threadIdx.x >> 4);
    const long totG = (long)gridDim.x * 16;

    float4 va[4];
    float ab[NGRADES];
    const int PI[4] = {0, 1, 1, 2};

    for (long row = G; row < nrows; row += totG) {
        row_grade_sumsq((const float4*)(x + row * MV_DIM + j * 16), va, bj, ab);

        const int nb   = (int)(row & 63);
        const int base = nb * NGRADES;

        float mrel[5];
#pragma unroll
        for (int k = 0; k < 5; ++k) {
            const int g  = bj + k;                       // runtime, <= 8
            const float q2 = pick9(ab, g) + EPS;
            mrel[k] = cA[base + g] + cB[base + g] * (1.0f / sqrtf(q2));
        }

        float4* po = (float4*)(out + row * MV_DIM + j * 16);
#pragma unroll
        for (int i = 0; i < 4; ++i) {
            float4 o;
            o.x = va[i].x * mrel[PI[i] + 0];
            o.y = va[i].y * mrel[PI[i] + 1];
            o.z = va[i].z * mrel[PI[i] + 1];
            o.w = va[i].w * mrel[PI[i] + 2];
            po[i] = o;
        }
    }
}

extern "C" void kernel_launch(void* const* d_in, const int* in_sizes, int n_in,
                              void* d_out, int out_size, void* d_ws, size_t ws_size,
                              hipStream_t stream) {
    const float* x      = (const float*)d_in[0];
    const float* gamma  = (const float*)d_in[1];
    const float* beta   = (const float*)d_in[2];
    const float* gscale = (const float*)d_in[3];
    float* out = (float*)d_out;

    const long nrows = (long)in_sizes[0] / MV_DIM;     // B * NB = 262144
    const float invB = 1.0f / (float)(nrows / NB);     // 1/4096

    float* stats = (float*)d_ws;                        // 2 * 576 floats
    float* coef  = stats + 2 * NB * NGRADES;            // 2 * 576 floats

    hipMemsetAsync(stats, 0, 2 * NB * NGRADES * sizeof(float), stream);

    // pass1: 1024 blocks * 16 groups = 16384 groups (stride % 64 == 0 -> nb const)
    cbn_pass1<<<1024, 256, 0, stream>>>(x, stats, nrows);
    cbn_finalize<<<3, 256, 0, stream>>>(stats, gamma, beta, gscale, coef, invB);
    // pass2: 2048 blocks * 16 groups = 32768 groups, 8 rows each
    cbn_pass2<<<2048, 256, 0, stream>>>(x, coef, out, nrows);
}